// Round 2
// baseline (80.284 us; speedup 1.0000x reference)
//
#include <hip/hip_runtime.h>
#include <hip/hip_fp16.h>

// ROI pooling: crop_and_resize (bilinear, 14x14) + 2x2 max pool -> (256,7,7,512) fp32
// feature_maps: (2,50,50,512) fp32 NHWC ; rois: (2,128,4) fp32
// reference permutes [1,0,3,2] -> y1=roi[1], x1=roi[0], y2=roi[3], x2=roi[2]
//
// R7: 2 output pixels per wave (R6's cache-policy pass was neutral -> roi_pool
// is NOT L2-BW-bound; 200 MB taps over ~28 us is only ~7 TB/s vs 34.5 ceiling).
// Revised theory: latency-bound. 12544 waves / 256 CU with ~16 resident
// waves/CU -> ~20K cyc/wave for 16 loads + ~150 VALU = ~95% stall. Fix: halve
// the wave count, give each wave TWO independent 16-load dep chains (2x MLP)
// and amortize the per-wave setup (rois s_load wait, ROI decode) over 2 pixels.
// Pairs are adjacent tasks: same ROI, usually same pooled row -> tap lines
// overlap in L1/L2. fp16 pipeline, cvt, NT stores, XCD swizzle unchanged.

constexpr int H = 50, W = 50, C = 512;
constexpr int POOLEDX = 7, KSIZE = 2, CROP = 14;
constexpr int RPB = 128;
constexpr int PIX = POOLEDX * POOLEDX;     // 49
constexpr int NROI = 2 * RPB;              // 256
constexpr int NTASK = NROI * PIX;          // 12544 output pixels
constexpr int NELEM = 2 * H * W * C;       // 2,560,000 floats
constexpr int NPAIR = NTASK / 2;           // 6272 wave-tasks
constexpr int NBLK  = NPAIR / 4;           // 1568 blocks (4 waves/block)
constexpr int NXCD  = 8;
constexpr int CHUNK = NBLK / NXCD;         // 196 (exact)

typedef _Float16 h8 __attribute__((ext_vector_type(8)));
typedef float    f4 __attribute__((ext_vector_type(4)));

// ---------- pre-pass: fm fp32 -> fp16 into workspace ----------
__global__ __launch_bounds__(256) void cvt_kernel(
    const float* __restrict__ in, __half* __restrict__ out)
{
    const int i = (blockIdx.x * 256 + threadIdx.x) * 8;
    const f4* in4 = reinterpret_cast<const f4*>(in + i);
    const f4 a = __builtin_nontemporal_load(in4);      // read-once fp32: don't cache
    const f4 b = __builtin_nontemporal_load(in4 + 1);
    _Float16 h[8];
    h[0] = (_Float16)a[0]; h[1] = (_Float16)a[1];
    h[2] = (_Float16)a[2]; h[3] = (_Float16)a[3];
    h[4] = (_Float16)b[0]; h[5] = (_Float16)b[1];
    h[6] = (_Float16)b[2]; h[7] = (_Float16)b[3];
    // normal (cached) store: fmh is the hot data the main kernel gathers from
    *reinterpret_cast<f4*>(out + i) = *reinterpret_cast<const f4*>(h);
}

// ---------- main: 4 waves/block, TWO output pixels per wave ----------
__global__ __launch_bounds__(256, 4) void roi_pool_kernel(
    const __half* __restrict__ fmh,
    const float* __restrict__ rois,
    float* __restrict__ out)
{
    const int wv   = __builtin_amdgcn_readfirstlane((int)(threadIdx.x >> 6));
    const int lane = threadIdx.x & 63;                  // channels 8*lane..

    // XCD-chunked swizzle (neutral but harmless; keeps L2 working set small)
    const int bid  = blockIdx.x;
    const int swz  = (bid & (NXCD - 1)) * CHUNK + (bid >> 3);
    const int t0   = (swz * 4 + wv) * 2;                // first of two tasks

    #pragma unroll
    for (int p = 0; p < 2; ++p) {
        const int task = t0 + p;                        // 0..12543
        const int n  = task / PIX;
        const int k  = task - n * PIX;
        const int ph = k / POOLEDX;
        const int pw = k - ph * POOLEDX;
        const int bat = n / RPB;

        const float rx1 = rois[n*4+0], ry1 = rois[n*4+1];
        const float rx2 = rois[n*4+2], ry2 = rois[n*4+3];
        const float ybase = ry1 * (float)(H - 1);
        const float xbase = rx1 * (float)(W - 1);
        const float ystep = ((ry2 - ry1) * (float)(H - 1)) / (float)(CROP - 1);
        const float xstep = ((rx2 - rx1) * (float)(W - 1)) / (float)(CROP - 1);

        // x-tap params (shared across both ky)
        int   x0i[KSIZE], x1i[KSIZE];
        float wx[KSIZE];
        bool  vx[KSIZE];
        #pragma unroll
        for (int kx = 0; kx < KSIZE; ++kx) {
            const float xs = xbase + (float)(pw * KSIZE + kx) * xstep;
            vx[kx] = (xs >= 0.0f) && (xs <= (float)(W - 1));
            const float xf = floorf(xs);
            wx[kx] = xs - xf;
            int xi = (int)xf; xi = min(max(xi, 0), W - 1);
            x0i[kx] = xi;
            x1i[kx] = min(xi + 1, W - 1);
        }

        const __half* base = fmh + (long)bat * (H * W) * C + lane * 8;

        h8 acc;
        #pragma unroll
        for (int c = 0; c < 8; ++c) acc[c] = (_Float16)(-60000.0f);

        #pragma unroll
        for (int ky = 0; ky < KSIZE; ++ky) {
            const float ys = ybase + (float)(ph * KSIZE + ky) * ystep;
            const bool  vy = (ys >= 0.0f) && (ys <= (float)(H - 1));
            const float yf = floorf(ys);
            const float wy = ys - yf;
            int y0 = (int)yf; y0 = min(max(y0, 0), H - 1);
            const int y1 = min(y0 + 1, H - 1);

            #pragma unroll
            for (int kx = 0; kx < KSIZE; ++kx) {
                const h8 t00 = *reinterpret_cast<const h8*>(base + (long)(y0 * W + x0i[kx]) * C);
                const h8 t01 = *reinterpret_cast<const h8*>(base + (long)(y0 * W + x1i[kx]) * C);
                const h8 t10 = *reinterpret_cast<const h8*>(base + (long)(y1 * W + x0i[kx]) * C);
                const h8 t11 = *reinterpret_cast<const h8*>(base + (long)(y1 * W + x1i[kx]) * C);

                // product-form bilinear in packed fp16
                const float wxk = wx[kx];
                const _Float16 w00 = (_Float16)((1.0f - wy) * (1.0f - wxk));
                const _Float16 w01 = (_Float16)((1.0f - wy) * wxk);
                const _Float16 w10 = (_Float16)(wy * (1.0f - wxk));
                const _Float16 w11 = (_Float16)(wy * wxk);

                h8 v = t00 * w00 + t01 * w01 + t10 * w10 + t11 * w11;

                if (!(vx[kx] && vy)) {                  // wave-uniform -> cndmask
                    #pragma unroll
                    for (int c = 0; c < 8; ++c) v[c] = (_Float16)0.0f;
                }

#if __has_builtin(__builtin_elementwise_max)
                acc = __builtin_elementwise_max(acc, v);
#else
                #pragma unroll
                for (int c = 0; c < 8; ++c) acc[c] = acc[c] > v[c] ? acc[c] : v[c];
#endif
            }
        }

        // epilogue: fp16 -> fp32, two nontemporal float4 stores (write-once)
        f4 o0, o1;
        o0[0] = (float)acc[0]; o0[1] = (float)acc[1]; o0[2] = (float)acc[2]; o0[3] = (float)acc[3];
        o1[0] = (float)acc[4]; o1[1] = (float)acc[5]; o1[2] = (float)acc[6]; o1[3] = (float)acc[7];
        f4* out4 = reinterpret_cast<f4*>(out) + (long)task * (C / 4) + lane * 2;
        __builtin_nontemporal_store(o0, out4);
        __builtin_nontemporal_store(o1, out4 + 1);
    }
}

extern "C" void kernel_launch(void* const* d_in, const int* in_sizes, int n_in,
                              void* d_out, int out_size, void* d_ws, size_t ws_size,
                              hipStream_t stream) {
    const float* fm   = (const float*)d_in[0];
    const float* rois = (const float*)d_in[1];
    float* out  = (float*)d_out;
    __half* fmh = (__half*)d_ws;                       // 5.12 MB << ws_size

    cvt_kernel<<<NELEM / (256 * 8), 256, 0, stream>>>(fm, fmh);     // 1250 blocks
    roi_pool_kernel<<<NBLK, 256, 0, stream>>>(fmh, rois, out);      // 1568 blocks
}

// Round 4
// 78.693 us; speedup vs baseline: 1.0202x; 1.0202x over previous
//
#include <hip/hip_runtime.h>
#include <hip/hip_fp16.h>

// ROI pooling: crop_and_resize (bilinear, 14x14) + 2x2 max pool -> (256,7,7,512) fp32
// feature_maps: (2,50,50,512) fp32 NHWC ; rois: (2,128,4) fp32
// reference permutes [1,0,3,2] -> y1=roi[1], x1=roi[0], y2=roi[3], x2=roi[2]
//
// R8b: retry of R8 (round-3 bench was an infra flake: "container failed twice",
// no compile/correctness signal). Theory unchanged:
// R6 (cache policy) and R7 (2 px/wave) were both neutral -> roi_pool is not
// BW-bound and not wave-MLP-bound. Remaining theory: under launch_bounds(256,4)'s
// 128-VGPR cap, the 16 independent tap loads (64 VGPR of data alone) can't all
// be in flight; the compiler batches them with full waitcnt drains -> ~3-4
// exposed L2/L3 latencies (~350cy) per pixel. Changes vs R6:
//  - __launch_bounds__(256, 2): VGPR budget 256. All 16 taps issued before any
//    consumption -> one exposed latency per pixel. 8 waves/CU still
//    issue-saturates the SIMDs once latency is single-exposure.
//  - readfirstlane'd tap offsets: y/x indices are wave-uniform; scalarizing
//    them moves 16 address calcs to SALU and frees VGPRs for tap data.
//  - valid-mask folded into the fp32 weight products (w *= m) instead of a
//    packed cndmask pass per tap.
// cvt, NT stores, XCD swizzle, 1 pixel/wave grid unchanged from R6.

constexpr int H = 50, W = 50, C = 512;
constexpr int POOLEDX = 7, KSIZE = 2, CROP = 14;
constexpr int RPB = 128;
constexpr int PIX = POOLEDX * POOLEDX;     // 49
constexpr int NROI = 2 * RPB;              // 256
constexpr int NTASK = NROI * PIX;          // 12544 output pixels
constexpr int NELEM = 2 * H * W * C;       // 2,560,000 floats
constexpr int NBLK  = NTASK / 4;           // 3136 blocks
constexpr int NXCD  = 8;
constexpr int CHUNK = NBLK / NXCD;         // 392 (exact)

typedef _Float16 h8 __attribute__((ext_vector_type(8)));
typedef float    f4 __attribute__((ext_vector_type(4)));

// ---------- pre-pass: fm fp32 -> fp16 into workspace ----------
__global__ __launch_bounds__(256) void cvt_kernel(
    const float* __restrict__ in, __half* __restrict__ out)
{
    const int i = (blockIdx.x * 256 + threadIdx.x) * 8;
    const f4* in4 = reinterpret_cast<const f4*>(in + i);
    const f4 a = __builtin_nontemporal_load(in4);      // read-once fp32: don't cache
    const f4 b = __builtin_nontemporal_load(in4 + 1);
    _Float16 h[8];
    h[0] = (_Float16)a[0]; h[1] = (_Float16)a[1];
    h[2] = (_Float16)a[2]; h[3] = (_Float16)a[3];
    h[4] = (_Float16)b[0]; h[5] = (_Float16)b[1];
    h[6] = (_Float16)b[2]; h[7] = (_Float16)b[3];
    *reinterpret_cast<f4*>(out + i) = *reinterpret_cast<const f4*>(h);
}

// ---------- main: 4 waves/block, one output pixel per wave ----------
__global__ __launch_bounds__(256, 2) void roi_pool_kernel(
    const __half* __restrict__ fmh,
    const float* __restrict__ rois,
    float* __restrict__ out)
{
    const int wv   = __builtin_amdgcn_readfirstlane((int)(threadIdx.x >> 6));
    const int lane = threadIdx.x & 63;                  // channels 8*lane..

    const int bid  = blockIdx.x;
    const int swz  = (bid & (NXCD - 1)) * CHUNK + (bid >> 3);
    const int task = swz * 4 + wv;                      // 0..12543

    const int n  = task / PIX;
    const int k  = task - n * PIX;
    const int ph = k / POOLEDX;
    const int pw = k - ph * POOLEDX;
    const int bat = n / RPB;

    const float rx1 = rois[n*4+0], ry1 = rois[n*4+1];
    const float rx2 = rois[n*4+2], ry2 = rois[n*4+3];
    const float ybase = ry1 * (float)(H - 1);
    const float xbase = rx1 * (float)(W - 1);
    const float ystep = ((ry2 - ry1) * (float)(H - 1)) / (float)(CROP - 1);
    const float xstep = ((rx2 - rx1) * (float)(W - 1)) / (float)(CROP - 1);

    // ---- tap parameters (all wave-uniform) ----
    int   x0i[KSIZE], x1i[KSIZE], y0i[KSIZE], y1i[KSIZE];
    float wxA[KSIZE], wyA[KSIZE];
    float mxA[KSIZE], myA[KSIZE];           // valid masks as 0/1 floats
    #pragma unroll
    for (int kx = 0; kx < KSIZE; ++kx) {
        const float xs = xbase + (float)(pw * KSIZE + kx) * xstep;
        mxA[kx] = ((xs >= 0.0f) && (xs <= (float)(W - 1))) ? 1.0f : 0.0f;
        const float xf = floorf(xs);
        wxA[kx] = xs - xf;
        int xi = (int)xf; xi = min(max(xi, 0), W - 1);
        x0i[kx] = __builtin_amdgcn_readfirstlane(xi);
        x1i[kx] = __builtin_amdgcn_readfirstlane(min(xi + 1, W - 1));
    }
    #pragma unroll
    for (int ky = 0; ky < KSIZE; ++ky) {
        const float ys = ybase + (float)(ph * KSIZE + ky) * ystep;
        myA[ky] = ((ys >= 0.0f) && (ys <= (float)(H - 1))) ? 1.0f : 0.0f;
        const float yf = floorf(ys);
        wyA[ky] = ys - yf;
        int yi = (int)yf; yi = min(max(yi, 0), H - 1);
        y0i[ky] = __builtin_amdgcn_readfirstlane(yi);
        y1i[ky] = __builtin_amdgcn_readfirstlane(min(yi + 1, H - 1));
    }

    const __half* base = fmh + (long)bat * (H * W) * C + lane * 8;

    // ---- phase 1: issue ALL 16 tap loads (independent; one waitcnt later) ----
    // fully scalar offsets (SGPR + imm), fully unrolled -> no scratch array
    const h8 t00a = *reinterpret_cast<const h8*>(base + (y0i[0] * W + x0i[0]) * C);
    const h8 t01a = *reinterpret_cast<const h8*>(base + (y0i[0] * W + x1i[0]) * C);
    const h8 t10a = *reinterpret_cast<const h8*>(base + (y1i[0] * W + x0i[0]) * C);
    const h8 t11a = *reinterpret_cast<const h8*>(base + (y1i[0] * W + x1i[0]) * C);
    const h8 t00b = *reinterpret_cast<const h8*>(base + (y0i[0] * W + x0i[1]) * C);
    const h8 t01b = *reinterpret_cast<const h8*>(base + (y0i[0] * W + x1i[1]) * C);
    const h8 t10b = *reinterpret_cast<const h8*>(base + (y1i[0] * W + x0i[1]) * C);
    const h8 t11b = *reinterpret_cast<const h8*>(base + (y1i[0] * W + x1i[1]) * C);
    const h8 t00c = *reinterpret_cast<const h8*>(base + (y0i[1] * W + x0i[0]) * C);
    const h8 t01c = *reinterpret_cast<const h8*>(base + (y0i[1] * W + x1i[0]) * C);
    const h8 t10c = *reinterpret_cast<const h8*>(base + (y1i[1] * W + x0i[0]) * C);
    const h8 t11c = *reinterpret_cast<const h8*>(base + (y1i[1] * W + x1i[0]) * C);
    const h8 t00d = *reinterpret_cast<const h8*>(base + (y0i[1] * W + x0i[1]) * C);
    const h8 t01d = *reinterpret_cast<const h8*>(base + (y0i[1] * W + x1i[1]) * C);
    const h8 t10d = *reinterpret_cast<const h8*>(base + (y1i[1] * W + x0i[1]) * C);
    const h8 t11d = *reinterpret_cast<const h8*>(base + (y1i[1] * W + x1i[1]) * C);

    // ---- phase 2: consume ----
    h8 acc;
    #pragma unroll
    for (int c = 0; c < 8; ++c) acc[c] = (_Float16)(-60000.0f);

    {
        // (ky=0, kx=0)
        const float wy = wyA[0], wxk = wxA[0], m = mxA[0] * myA[0];
        const _Float16 w00 = (_Float16)((1.0f - wy) * (1.0f - wxk) * m);
        const _Float16 w01 = (_Float16)((1.0f - wy) * wxk * m);
        const _Float16 w10 = (_Float16)(wy * (1.0f - wxk) * m);
        const _Float16 w11 = (_Float16)(wy * wxk * m);
        const h8 v = t00a * w00 + t01a * w01 + t10a * w10 + t11a * w11;
        acc = __builtin_elementwise_max(acc, v);
    }
    {
        // (ky=0, kx=1)
        const float wy = wyA[0], wxk = wxA[1], m = mxA[1] * myA[0];
        const _Float16 w00 = (_Float16)((1.0f - wy) * (1.0f - wxk) * m);
        const _Float16 w01 = (_Float16)((1.0f - wy) * wxk * m);
        const _Float16 w10 = (_Float16)(wy * (1.0f - wxk) * m);
        const _Float16 w11 = (_Float16)(wy * wxk * m);
        const h8 v = t00b * w00 + t01b * w01 + t10b * w10 + t11b * w11;
        acc = __builtin_elementwise_max(acc, v);
    }
    {
        // (ky=1, kx=0)
        const float wy = wyA[1], wxk = wxA[0], m = mxA[0] * myA[1];
        const _Float16 w00 = (_Float16)((1.0f - wy) * (1.0f - wxk) * m);
        const _Float16 w01 = (_Float16)((1.0f - wy) * wxk * m);
        const _Float16 w10 = (_Float16)(wy * (1.0f - wxk) * m);
        const _Float16 w11 = (_Float16)(wy * wxk * m);
        const h8 v = t00c * w00 + t01c * w01 + t10c * w10 + t11c * w11;
        acc = __builtin_elementwise_max(acc, v);
    }
    {
        // (ky=1, kx=1)
        const float wy = wyA[1], wxk = wxA[1], m = mxA[1] * myA[1];
        const _Float16 w00 = (_Float16)((1.0f - wy) * (1.0f - wxk) * m);
        const _Float16 w01 = (_Float16)((1.0f - wy) * wxk * m);
        const _Float16 w10 = (_Float16)(wy * (1.0f - wxk) * m);
        const _Float16 w11 = (_Float16)(wy * wxk * m);
        const h8 v = t00d * w00 + t01d * w01 + t10d * w10 + t11d * w11;
        acc = __builtin_elementwise_max(acc, v);
    }

    // epilogue: fp16 -> fp32, two nontemporal float4 stores (write-once)
    f4 o0, o1;
    o0[0] = (float)acc[0]; o0[1] = (float)acc[1]; o0[2] = (float)acc[2]; o0[3] = (float)acc[3];
    o1[0] = (float)acc[4]; o1[1] = (float)acc[5]; o1[2] = (float)acc[6]; o1[3] = (float)acc[7];
    f4* out4 = reinterpret_cast<f4*>(out) + (long)task * (C / 4) + lane * 2;
    __builtin_nontemporal_store(o0, out4);
    __builtin_nontemporal_store(o1, out4 + 1);
}

extern "C" void kernel_launch(void* const* d_in, const int* in_sizes, int n_in,
                              void* d_out, int out_size, void* d_ws, size_t ws_size,
                              hipStream_t stream) {
    const float* fm   = (const float*)d_in[0];
    const float* rois = (const float*)d_in[1];
    float* out  = (float*)d_out;
    __half* fmh = (__half*)d_ws;                       // 5.12 MB << ws_size

    cvt_kernel<<<NELEM / (256 * 8), 256, 0, stream>>>(fm, fmh);     // 1250 blocks
    roi_pool_kernel<<<NBLK, 256, 0, stream>>>(fmh, rois, out);      // 3136 blocks
}